// Round 3
// baseline (425.929 us; speedup 1.0000x reference)
//
#include <hip/hip_runtime.h>

#define TS 524288u          // 2^19
#define PRIME 2654435761u

typedef float vfloat4 __attribute__((ext_vector_type(4)));

// floor(16 * fl32(g)^l), g = 64^(1/15); fl32(g) rounds UP so the exact-integer
// levels (5,10,15) floor to 64/256/1024 under correctly-rounded powf (= numpy).
__device__ __constant__ float c_scale[16] = {
    16.f, 21.f, 27.f, 36.f, 48.f, 64.f, 84.f, 111.f,
    147.f, 194.f, 256.f, 337.f, 445.f, 588.f, 776.f, 1024.f
};

__global__ __launch_bounds__(256) void hashenc_kernel(
    const float2* __restrict__ x,
    const float2* __restrict__ tab,
    vfloat4* __restrict__ out)
{
    unsigned t  = blockIdx.x * 256u + threadIdx.x;   // [0, 4M)
    unsigned lq = t & 3u;                            // level quad: levels 4lq..4lq+3
    unsigned p  = t >> 2;                            // point id

    float2 xy = x[p];
    unsigned l0 = lq << 2;

    // Phase 1: compute all 16 addresses, issue all 16 gathers (MLP).
    float2 f0[4], f1[4], f2[4], f3[4];
    float ox[4], oy[4];

#pragma unroll
    for (int k = 0; k < 4; ++k) {
        unsigned l = l0 + (unsigned)k;
        float s = c_scale[l];

        float sx = xy.x * s;
        float sy = xy.y * s;
        float fxf = floorf(sx), fyf = floorf(sy);
        float cxf = ceilf(sx),  cyf = ceilf(sy);
        ox[k] = sx - fxf;
        oy[k] = sy - fyf;

        unsigned fx = (unsigned)(int)fxf, fy = (unsigned)(int)fyf;
        unsigned cx = (unsigned)(int)cxf, cy = (unsigned)(int)cyf;

        unsigned hcy = cy * PRIME;
        unsigned hfy = fy * PRIME;
        unsigned base = l << 19;

        // v0=(cx,cy) v1=(cx,fy) v2=(fx,cy) v3=(fx,fy) — per reference
        f0[k] = tab[((cx ^ hcy) & (TS - 1u)) | base];
        f1[k] = tab[((cx ^ hfy) & (TS - 1u)) | base];
        f2[k] = tab[((fx ^ hcy) & (TS - 1u)) | base];
        f3[k] = tab[((fx ^ hfy) & (TS - 1u)) | base];
    }

    // Phase 2: blend (replicates reference formula exactly).
    vfloat4 r[2];
#pragma unroll
    for (int k = 0; k < 4; ++k) {
        float wox = 1.0f - ox[k], woy = 1.0f - oy[k];
        float f03x = f0[k].x * ox[k] + f3[k].x * wox;
        float f03y = f0[k].y * ox[k] + f3[k].y * wox;
        float f12x = f1[k].x * ox[k] + f2[k].x * wox;
        float f12y = f1[k].y * ox[k] + f2[k].y * wox;
        float ex = f03x * oy[k] + f12x * woy;
        float ey = f03y * oy[k] + f12y * woy;
        if ((k & 1) == 0) { r[k >> 1].x = ex; r[k >> 1].y = ey; }
        else              { r[k >> 1].z = ex; r[k >> 1].w = ey; }
    }

    // out float4 index: point p, level-pairs (2lq, 2lq+1) → p*8 + lq*2 (+1).
    unsigned o = p * 8u + lq * 2u;
    __builtin_nontemporal_store(r[0], &out[o]);
    __builtin_nontemporal_store(r[1], &out[o + 1]);
}

extern "C" void kernel_launch(void* const* d_in, const int* in_sizes, int n_in,
                              void* d_out, int out_size, void* d_ws, size_t ws_size,
                              hipStream_t stream)
{
    const float2* x   = (const float2*)d_in[0];
    const float2* tab = (const float2*)d_in[1];
    vfloat4* out = (vfloat4*)d_out;

    unsigned n_threads = (unsigned)((size_t)out_size / 8);   // 4,194,304
    unsigned n_blocks  = n_threads / 256u;                   // 16,384
    hashenc_kernel<<<n_blocks, 256, 0, stream>>>(x, tab, out);
}

// Round 4
// 363.525 us; speedup vs baseline: 1.1717x; 1.1717x over previous
//
#include <hip/hip_runtime.h>

#define TS 524288u          // 2^19
#define PRIME 2654435761u
#define NPTS 1048576u

typedef float vfloat4 __attribute__((ext_vector_type(4)));

// floor(16 * fl32(g)^l), g = 64^(1/15); fl32(g) rounds UP so the exact-integer
// levels (5,10,15) floor to 64/256/1024 under correctly-rounded powf (= numpy).
__device__ __constant__ float c_scale[16] = {
    16.f, 21.f, 27.f, 36.f, 48.f, 64.f, 84.f, 111.f,
    147.f, 194.f, 256.f, 337.f, 445.f, 588.f, 776.f, 1024.f
};

// Staged levels 0-3 (res 16,21,27,36 -> grid widths 17,22,28,37).
#define W0 17
#define W1 22
#define W2 28
#define W3 37
#define B0 0
#define B1 (B0 + W0*W0)        // 289
#define B2 (B1 + W1*W1)        // 773
#define B3 (B2 + W2*W2)        // 1557
#define NSTAGE (B3 + W3*W3)    // 2926 float2 = 23408 B

__global__ __launch_bounds__(256) void hashenc_kernel(
    const float2* __restrict__ x,
    const float2* __restrict__ tab,
    vfloat4* __restrict__ out,
    unsigned pts_per_block)
{
    __shared__ float2 lds[NSTAGE];
    unsigned tid = threadIdx.x;

    // ---- Stage levels 0-3 into LDS (identical values to tab[hash(v)]) ----
    // i == vy*W + vx by construction; consecutive vx share a 64B line (xor hash).
#define STAGE(L, W, B)                                                  \
    for (unsigned i = tid; i < (unsigned)((W)*(W)); i += 256u) {        \
        unsigned vy = i / (unsigned)(W), vx = i % (unsigned)(W);        \
        unsigned h = ((vx ^ (vy * PRIME)) & (TS - 1u)) | ((unsigned)(L) << 19); \
        lds[(B) + i] = tab[h];                                          \
    }
    STAGE(0, W0, B0)
    STAGE(1, W1, B1)
    STAGE(2, W2, B2)
    STAGE(3, W3, B3)
#undef STAGE
    __syncthreads();

    const unsigned lq = tid & 3u;          // level quad: levels 4lq..4lq+3
    const unsigned lane_p = tid >> 2;      // 0..63: point slot within iteration
    const unsigned l0 = lq << 2;
    const unsigned bs = blockIdx.x * pts_per_block;
    unsigned be = bs + pts_per_block;
    if (be > NPTS) be = NPTS;

    const unsigned Wk[4] = { W0, W1, W2, W3 };
    const unsigned Bk[4] = { B0, B1, B2, B3 };

    for (unsigned p = bs + lane_p; p < be; p += 64u) {
        float2 xy = x[p];
        vfloat4 r[2];

        if (lq == 0u) {
            // ---- levels 0-3 from LDS ----
#pragma unroll
            for (int k = 0; k < 4; ++k) {
                float s = c_scale[k];
                float sx = xy.x * s, sy = xy.y * s;
                float fxf = floorf(sx), fyf = floorf(sy);
                float cxf = ceilf(sx),  cyf = ceilf(sy);
                float ox = sx - fxf, oy = sy - fyf;
                unsigned fx = (unsigned)(int)fxf, fy = (unsigned)(int)fyf;
                unsigned cx = (unsigned)(int)cxf, cy = (unsigned)(int)cyf;
                unsigned w = Wk[k], b = Bk[k];
                float2 f0 = lds[b + cy * w + cx];
                float2 f1 = lds[b + fy * w + cx];
                float2 f2 = lds[b + cy * w + fx];
                float2 f3 = lds[b + fy * w + fx];
                float wox = 1.0f - ox, woy = 1.0f - oy;
                float f03x = f0.x * ox + f3.x * wox;
                float f03y = f0.y * ox + f3.y * wox;
                float f12x = f1.x * ox + f2.x * wox;
                float f12y = f1.y * ox + f2.y * wox;
                float ex = f03x * oy + f12x * woy;
                float ey = f03y * oy + f12y * woy;
                if ((k & 1) == 0) { r[k >> 1].x = ex; r[k >> 1].y = ey; }
                else              { r[k >> 1].z = ex; r[k >> 1].w = ey; }
            }
        } else {
            // ---- levels 4lq..4lq+3 from global (hashed gathers) ----
#pragma unroll
            for (int k = 0; k < 4; ++k) {
                unsigned l = l0 + (unsigned)k;
                float s = c_scale[l];
                float sx = xy.x * s, sy = xy.y * s;
                float fxf = floorf(sx), fyf = floorf(sy);
                float cxf = ceilf(sx),  cyf = ceilf(sy);
                float ox = sx - fxf, oy = sy - fyf;
                unsigned fx = (unsigned)(int)fxf, fy = (unsigned)(int)fyf;
                unsigned cx = (unsigned)(int)cxf, cy = (unsigned)(int)cyf;
                unsigned hcy = cy * PRIME, hfy = fy * PRIME;
                unsigned base = l << 19;
                float2 f0 = tab[((cx ^ hcy) & (TS - 1u)) | base];
                float2 f1 = tab[((cx ^ hfy) & (TS - 1u)) | base];
                float2 f2 = tab[((fx ^ hcy) & (TS - 1u)) | base];
                float2 f3 = tab[((fx ^ hfy) & (TS - 1u)) | base];
                float wox = 1.0f - ox, woy = 1.0f - oy;
                float f03x = f0.x * ox + f3.x * wox;
                float f03y = f0.y * ox + f3.y * wox;
                float f12x = f1.x * ox + f2.x * wox;
                float f12y = f1.y * ox + f2.y * wox;
                float ex = f03x * oy + f12x * woy;
                float ey = f03y * oy + f12y * woy;
                if ((k & 1) == 0) { r[k >> 1].x = ex; r[k >> 1].y = ey; }
                else              { r[k >> 1].z = ex; r[k >> 1].w = ey; }
            }
        }

        // out float4 index: p*8 + lq*2 (+1). Consecutive tid -> contiguous 32B
        // per thread, wave covers 2KB contiguous -> fully coalesced.
        unsigned o = p * 8u + lq * 2u;
        __builtin_nontemporal_store(r[0], &out[o]);
        __builtin_nontemporal_store(r[1], &out[o + 1]);
    }
}

extern "C" void kernel_launch(void* const* d_in, const int* in_sizes, int n_in,
                              void* d_out, int out_size, void* d_ws, size_t ws_size,
                              hipStream_t stream)
{
    const float2* x   = (const float2*)d_in[0];
    const float2* tab = (const float2*)d_in[1];
    vfloat4* out = (vfloat4*)d_out;

    const unsigned n_blocks = 1536u;                       // ~6-7 blocks/CU resident
    const unsigned ppb = (NPTS + n_blocks - 1u) / n_blocks; // 683
    hashenc_kernel<<<n_blocks, 256, 0, stream>>>(x, tab, out, ppb);
}